// Round 1
// baseline (269.219 us; speedup 1.0000x reference)
//
#include <hip/hip_runtime.h>

// Problem constants (match reference setup_inputs()).
#define B_SZ   2048
#define F_IN   1024
#define R_EMB  1024
#define F_OUT  1024
#define F_MID  2048
#define NNZ_E  65536
#define NNZ_W  131072
#define NNZ_B  512

__global__ void k_zero(float* __restrict__ p, int n) {
    int i = blockIdx.x * blockDim.x + threadIdx.x;
    if (i < n) p[i] = 0.0f;
}

__global__ void k_hist(const int* __restrict__ rows, int nnz, int* __restrict__ counts) {
    int i = blockIdx.x * blockDim.x + threadIdx.x;
    if (i < nnz) atomicAdd(&counts[rows[i]], 1);
}

// Exclusive scan of 1024 counts -> row_start[1025] and a mutable cursor copy.
__global__ void k_scan1024(const int* __restrict__ counts,
                           int* __restrict__ row_start,
                           int* __restrict__ cursor) {
    __shared__ int buf[2][1024];
    int t = threadIdx.x;
    buf[0][t] = counts[t];
    __syncthreads();
    int cur = 0;
    for (int off = 1; off < 1024; off <<= 1) {
        int v = buf[cur][t];
        if (t >= off) v += buf[cur][t - off];
        buf[cur ^ 1][t] = v;
        cur ^= 1;
        __syncthreads();
    }
    int excl = (t == 0) ? 0 : buf[cur][t - 1];
    row_start[t] = excl;
    cursor[t]    = excl;
    if (t == 1023) row_start[1024] = buf[cur][1023];
}

__global__ void k_scatter(const int* __restrict__ rows, const int* __restrict__ cols,
                          const float* __restrict__ vals, int nnz,
                          int* __restrict__ cursor,
                          int* __restrict__ ocol, float* __restrict__ oval) {
    int i = blockIdx.x * blockDim.x + threadIdx.x;
    if (i < nnz) {
        int r   = rows[i];
        int pos = atomicAdd(&cursor[r], 1);
        ocol[pos] = cols[i];
        oval[pos] = vals[i];
    }
}

__global__ void k_bias(const int* __restrict__ idx, const float* __restrict__ vals,
                       float* __restrict__ bias) {
    int i = blockIdx.x * blockDim.x + threadIdx.x;
    if (i < NNZ_B) atomicAdd(&bias[idx[i]], vals[i]);
}

// Tiled transpose: in[R, C] -> out[C, R].  grid = (C/32, R/32), block = (32, 8).
__global__ void k_transpose(const float* __restrict__ in, float* __restrict__ out,
                            int R, int C) {
    __shared__ float tile[32][33];
    int c0 = blockIdx.x * 32, r0 = blockIdx.y * 32;
    int tx = threadIdx.x, ty = threadIdx.y;
    #pragma unroll
    for (int i = 0; i < 4; ++i) {
        int r = ty + i * 8;
        tile[r][tx] = in[(size_t)(r0 + r) * C + (c0 + tx)];
    }
    __syncthreads();
    #pragma unroll
    for (int i = 0; i < 4; ++i) {
        int c = ty + i * 8;
        out[(size_t)(c0 + c) * R + (r0 + tx)] = tile[tx][c];
    }
}

// CSR-row spmm on feature-major activations.
// xT: [nfeat, B] (feature-major).  outT: [n_rows, B].
// One block per (row, batch-tile of 1024); each thread accumulates 4 batch elems.
template <bool RELU, bool BIAS>
__global__ void k_spmm(const float* __restrict__ xT,
                       const int* __restrict__ row_start,
                       const int* __restrict__ cols,
                       const float* __restrict__ vals,
                       const float* __restrict__ bias,
                       float* __restrict__ outT) {
    int r = blockIdx.x;
    int b = (blockIdx.y * blockDim.x + threadIdx.x) * 4;
    int s = row_start[r], e = row_start[r + 1];
    float4 acc = make_float4(0.f, 0.f, 0.f, 0.f);
    for (int k = s; k < e; ++k) {
        int   c = cols[k];
        float v = vals[k];
        float4 xv = *reinterpret_cast<const float4*>(xT + (size_t)c * B_SZ + b);
        acc.x = fmaf(v, xv.x, acc.x);
        acc.y = fmaf(v, xv.y, acc.y);
        acc.z = fmaf(v, xv.z, acc.z);
        acc.w = fmaf(v, xv.w, acc.w);
    }
    if (BIAS) {
        float bv = bias[r];
        acc.x += bv; acc.y += bv; acc.z += bv; acc.w += bv;
    }
    if (RELU) {
        acc.x = fmaxf(acc.x, 0.f); acc.y = fmaxf(acc.y, 0.f);
        acc.z = fmaxf(acc.z, 0.f); acc.w = fmaxf(acc.w, 0.f);
    }
    *reinterpret_cast<float4*>(outT + (size_t)r * B_SZ + b) = acc;
}

extern "C" void kernel_launch(void* const* d_in, const int* in_sizes, int n_in,
                              void* d_out, int out_size, void* d_ws, size_t ws_size,
                              hipStream_t stream) {
    const float* x          = (const float*)d_in[0];
    const int*   embed_rows = (const int*)  d_in[1];
    const int*   embed_cols = (const int*)  d_in[2];
    const float* embed_vals = (const float*)d_in[3];
    const int*   w_rows     = (const int*)  d_in[4];
    const int*   w_cols     = (const int*)  d_in[5];
    const float* w_vals     = (const float*)d_in[6];
    const int*   bias_idx   = (const int*)  d_in[7];
    const float* bias_vals  = (const float*)d_in[8];
    float* out = (float*)d_out;

    // Workspace layout.
    float* x2T    = (float*)d_ws;                          // [F_MID, B]  16 MB (rows 0..F_IN-1 = xT, rows F_IN.. = hT)
    float* outT   = x2T + (size_t)F_MID * B_SZ;            // [F_OUT, B]   8 MB
    int*   se_col = (int*)(outT + (size_t)F_OUT * B_SZ);   // NNZ_E
    float* se_val = (float*)(se_col + NNZ_E);              // NNZ_E
    int*   sw_col = (int*)(se_val + NNZ_E);                // NNZ_W
    float* sw_val = (float*)(sw_col + NNZ_W);              // NNZ_W
    int*   counts_e = (int*)(sw_val + NNZ_W);              // 1024
    int*   counts_w = counts_e + 1024;                     // 1024
    float* bias_d   = (float*)(counts_w + 1024);           // 1024  (contiguous with counts for one zero pass)
    int*   rs_e     = (int*)(bias_d + 1024);               // 1025
    int*   rs_w     = rs_e + 1025;                         // 1025
    int*   cur_e    = rs_w + 1025;                         // 1024
    int*   cur_w    = cur_e + 1024;                        // 1024

    // 1. zero counts_e | counts_w | bias_d (3072 contiguous words)
    k_zero<<<12, 256, 0, stream>>>((float*)counts_e, 3072);

    // 2. row histograms
    k_hist<<<NNZ_E / 256, 256, 0, stream>>>(embed_rows, NNZ_E, counts_e);
    k_hist<<<NNZ_W / 256, 256, 0, stream>>>(w_rows,     NNZ_W, counts_w);

    // 3. exclusive scans -> CSR row starts + scatter cursors
    k_scan1024<<<1, 1024, 0, stream>>>(counts_e, rs_e, cur_e);
    k_scan1024<<<1, 1024, 0, stream>>>(counts_w, rs_w, cur_w);

    // 4. scatter nnz into row-sorted order
    k_scatter<<<NNZ_E / 256, 256, 0, stream>>>(embed_rows, embed_cols, embed_vals,
                                               NNZ_E, cur_e, se_col, se_val);
    k_scatter<<<NNZ_W / 256, 256, 0, stream>>>(w_rows, w_cols, w_vals,
                                               NNZ_W, cur_w, sw_col, sw_val);

    // 5. densify bias
    k_bias<<<NNZ_B / 256, 256, 0, stream>>>(bias_idx, bias_vals, bias_d);

    // 6. x [B, F_IN] -> xT (rows 0..F_IN-1 of x2T)
    k_transpose<<<dim3(F_IN / 32, B_SZ / 32), dim3(32, 8), 0, stream>>>(x, x2T, B_SZ, F_IN);

    // 7. hT = relu(E-spmm), written into rows F_IN..F_MID-1 of x2T
    k_spmm<true, false><<<dim3(R_EMB, B_SZ / 1024), 256, 0, stream>>>(
        x2T, rs_e, se_col, se_val, nullptr, x2T + (size_t)F_IN * B_SZ);

    // 8. outT = W-spmm(x2T) + bias
    k_spmm<false, true><<<dim3(F_OUT, B_SZ / 1024), 256, 0, stream>>>(
        x2T, rs_w, sw_col, sw_val, bias_d, outT);

    // 9. outT [F_OUT, B] -> out [B, F_OUT]
    k_transpose<<<dim3(B_SZ / 32, F_OUT / 32), dim3(32, 8), 0, stream>>>(outT, out, F_OUT, B_SZ);
}

// Round 2
// 87.478 us; speedup vs baseline: 3.0776x; 3.0776x over previous
//
#include <hip/hip_runtime.h>
#include <hip/hip_bf16.h>

#define B_SZ   2048
#define F_IN   1024
#define R_EMB  1024
#define F_OUT  1024
#define F_MID  2048
#define NNZ_E  65536
#define NNZ_W  131072
#define NNZ_B  512

typedef __bf16 bf16x8 __attribute__((ext_vector_type(8)));
typedef float  f32x4  __attribute__((ext_vector_type(4)));

__device__ inline void gload16(const void* g, void* l) {
    __builtin_amdgcn_global_load_lds(
        (const __attribute__((address_space(1))) void*)g,
        (__attribute__((address_space(3))) void*)l, 16, 0, 0);
}

__device__ inline ushort f2bf(float v) {
    __hip_bfloat16 h = __float2bfloat16(v);
    return *reinterpret_cast<ushort*>(&h);
}

__global__ void k_zero4(float4* __restrict__ p, int n) {
    int i = blockIdx.x * blockDim.x + threadIdx.x;
    if (i < n) p[i] = make_float4(0.f, 0.f, 0.f, 0.f);
}

__global__ void k_scatter_add(const int* __restrict__ rows, const int* __restrict__ cols,
                              const float* __restrict__ vals, int nnz, int ldd,
                              float* __restrict__ dense) {
    int i = blockIdx.x * blockDim.x + threadIdx.x;
    if (i < nnz) atomicAdd(&dense[(size_t)rows[i] * ldd + cols[i]], vals[i]);
}

__global__ void k_bias(const int* __restrict__ idx, const float* __restrict__ vals,
                       float* __restrict__ bias) {
    int i = blockIdx.x * blockDim.x + threadIdx.x;
    if (i < NNZ_B) atomicAdd(&bias[idx[i]], vals[i]);
}

// x [2048][1024] f32 -> bf16 into x2 left half (row stride F_MID).
__global__ void k_cvt_x(const float* __restrict__ x, ushort* __restrict__ x2) {
    int i = blockIdx.x * blockDim.x + threadIdx.x;     // [0, 2048*1024/4)
    int row = i >> 8, c4 = i & 255;                    // 256 float4 per row
    float4 v = ((const float4*)x)[i];
    ushort4 o = make_ushort4(f2bf(v.x), f2bf(v.y), f2bf(v.z), f2bf(v.w));
    ((ushort4*)x2)[(size_t)row * (F_MID / 4) + c4] = o;
}

// contiguous f32 -> bf16
__global__ void k_cvt(const float4* __restrict__ s, ushort* __restrict__ d, int n4) {
    int i = blockIdx.x * blockDim.x + threadIdx.x;
    if (i < n4) {
        float4 v = s[i];
        ((ushort4*)d)[i] = make_ushort4(f2bf(v.x), f2bf(v.y), f2bf(v.z), f2bf(v.w));
    }
}

// C[M,N] = A[M,K] * Bm[N,K]^T.  BM=128, BN=64, BK=64; 256 thr = 4 waves (2x2),
// each wave owns 64x32 = 4x2 fragments of 16x16.  m97-style single-buffer loop.
template <bool RELU_BF16>
__global__ __launch_bounds__(256)
void k_gemm(const ushort* __restrict__ A, int lda,
            const ushort* __restrict__ Bm, int ldb,
            int K,
            const float* __restrict__ bias,
            float* __restrict__ outF,
            ushort* __restrict__ outH, int ldh)
{
    constexpr int BM = 128, BN = 64, BK = 64;
    __shared__ ushort lA[BM * BK];   // [128][64] bf16, linear
    __shared__ ushort lB[BN * BK];   // [64][64]
    const int tid = threadIdx.x;
    const int w = tid >> 6, l = tid & 63;
    const int m0 = blockIdx.x * BM, n0 = blockIdx.y * BN;
    const int wr = w >> 1, wc = w & 1;
    const int srow = w * 8 + (l >> 3);     // staging row within 32-row slab
    const int scol = (l & 7) * 8;          // staging col (elements)
    const int la = l & 15, lk = (l >> 4) * 8;

    f32x4 acc[4][2] = {};

    for (int k0 = 0; k0 < K; k0 += BK) {
        const ushort* gA = A  + (size_t)(m0 + srow) * lda + (k0 + scol);
        const ushort* gB = Bm + (size_t)(n0 + srow) * ldb + (k0 + scol);
        #pragma unroll
        for (int i = 0; i < 4; ++i)
            gload16(gA + (size_t)(i * 32) * lda, lA + i * 2048 + w * 512 + l * 8);
        #pragma unroll
        for (int i = 0; i < 2; ++i)
            gload16(gB + (size_t)(i * 32) * ldb, lB + i * 2048 + w * 512 + l * 8);
        __syncthreads();   // drains vmcnt before barrier

        #pragma unroll
        for (int ks = 0; ks < 2; ++ks) {
            bf16x8 af[4], bfr[2];
            const int kb = ks * 32 + lk;
            #pragma unroll
            for (int m = 0; m < 4; ++m)
                af[m] = *(const bf16x8*)(lA + (wr * 64 + m * 16 + la) * BK + kb);
            #pragma unroll
            for (int n = 0; n < 2; ++n)
                bfr[n] = *(const bf16x8*)(lB + (wc * 32 + n * 16 + la) * BK + kb);
            #pragma unroll
            for (int m = 0; m < 4; ++m)
                #pragma unroll
                for (int n = 0; n < 2; ++n)
                    acc[m][n] = __builtin_amdgcn_mfma_f32_16x16x32_bf16(
                        af[m], bfr[n], acc[m][n], 0, 0, 0);
        }
        __syncthreads();
    }

    const int lr = (l >> 4) * 4;
    #pragma unroll
    for (int m = 0; m < 4; ++m) {
        #pragma unroll
        for (int n = 0; n < 2; ++n) {
            const int col = n0 + wc * 32 + n * 16 + la;
            const float bv = RELU_BF16 ? 0.f : bias[col];
            #pragma unroll
            for (int j = 0; j < 4; ++j) {
                const int row = m0 + wr * 64 + m * 16 + lr + j;
                float v = acc[m][n][j];
                if (RELU_BF16) {
                    outH[(size_t)row * ldh + col] = f2bf(fmaxf(v, 0.f));
                } else {
                    outF[(size_t)row * F_OUT + col] = v + bv;
                }
            }
        }
    }
}

extern "C" void kernel_launch(void* const* d_in, const int* in_sizes, int n_in,
                              void* d_out, int out_size, void* d_ws, size_t ws_size,
                              hipStream_t stream) {
    const float* x          = (const float*)d_in[0];
    const int*   embed_rows = (const int*)  d_in[1];
    const int*   embed_cols = (const int*)  d_in[2];
    const float* embed_vals = (const float*)d_in[3];
    const int*   w_rows     = (const int*)  d_in[4];
    const int*   w_cols     = (const int*)  d_in[5];
    const float* w_vals     = (const float*)d_in[6];
    const int*   bias_idx   = (const int*)  d_in[7];
    const float* bias_vals  = (const float*)d_in[8];
    float* out = (float*)d_out;

    // Workspace layout (23.1 MB total):
    //   [0,8M)        x2 bf16 [2048][2048]  (left=x, right=relu h)
    //   [8M,16M)      W_f32   [1024][2048]
    //   [16M,20M)     E_f32   [1024][1024]  -> reused as W_bf16 after E convert
    //   [20M,20M+4K)  bias f32 [1024]
    //   [+2M)         E_bf16  [1024][1024]
    char* ws = (char*)d_ws;
    ushort* x2    = (ushort*)ws;
    float*  Wf    = (float*)(ws + (8u << 20));
    float*  Ef    = (float*)(ws + (16u << 20));
    float*  biasd = (float*)(ws + (20u << 20));
    ushort* Ebf   = (ushort*)(ws + (20u << 20) + 4096);
    ushort* Wbf   = (ushort*)(ws + (16u << 20));   // aliases Ef (used after E convert)

    // 1. zero W_f32 | E_f32 | bias  (contiguous 12 MB + 4 KB = 786688 float4)
    k_zero4<<<786688 / 256, 256, 0, stream>>>((float4*)(ws + (8u << 20)), 786688);

    // 2. densify (atomicAdd handles duplicate (r,c) pairs)
    k_scatter_add<<<NNZ_E / 256, 256, 0, stream>>>(embed_rows, embed_cols, embed_vals,
                                                   NNZ_E, F_IN, Ef);
    k_scatter_add<<<NNZ_W / 256, 256, 0, stream>>>(w_rows, w_cols, w_vals,
                                                   NNZ_W, F_MID, Wf);
    k_bias<<<NNZ_B / 256, 256, 0, stream>>>(bias_idx, bias_vals, biasd);

    // 3. convert to bf16 (E first — its f32 buffer is then reused for W_bf16)
    k_cvt_x<<<(B_SZ * F_IN / 4) / 256, 256, 0, stream>>>(x, x2);
    k_cvt<<<(R_EMB * F_IN / 4) / 256, 256, 0, stream>>>((const float4*)Ef, Ebf,
                                                        R_EMB * F_IN / 4);
    k_cvt<<<(F_OUT * F_MID / 4) / 256, 256, 0, stream>>>((const float4*)Wf, Wbf,
                                                         F_OUT * F_MID / 4);

    // 4. GEMM1: h = relu(x @ E^T) -> bf16 into x2 right half.  M=2048,N=1024,K=1024
    k_gemm<true><<<dim3(16, 16), 256, 0, stream>>>(
        x2, F_MID, Ebf, F_IN, F_IN, nullptr, nullptr, x2 + F_IN, F_MID);

    // 5. GEMM2: out = x2 @ W^T + bias.  M=2048,N=1024,K=2048
    k_gemm<false><<<dim3(16, 16), 256, 0, stream>>>(
        x2, F_MID, Wbf, F_MID, F_MID, biasd, out, nullptr, 0);
}

// Round 3
// 60.052 us; speedup vs baseline: 4.4831x; 1.4567x over previous
//
#include <hip/hip_runtime.h>
#include <hip/hip_bf16.h>

#define B_SZ   2048
#define F_IN   1024
#define R_EMB  1024
#define F_OUT  1024
#define F_MID  2048
#define NNZ_E  65536
#define NNZ_W  131072
#define NNZ_B  512

typedef __bf16 bf16x8 __attribute__((ext_vector_type(8)));
typedef float  f32x4  __attribute__((ext_vector_type(4)));

__device__ inline void gload16(const void* g, void* l) {
    __builtin_amdgcn_global_load_lds(
        (const __attribute__((address_space(1))) void*)g,
        (__attribute__((address_space(3))) void*)l, 16, 0, 0);
}

__device__ inline ushort f2bf(float v) {
    __hip_bfloat16 h = __float2bfloat16(v);
    return *reinterpret_cast<ushort*>(&h);
}

__global__ void k_zero4(float4* __restrict__ p, int n) {
    int i = blockIdx.x * blockDim.x + threadIdx.x;
    if (i < n) p[i] = make_float4(0.f, 0.f, 0.f, 0.f);
}

// One launch for all three scatter-adds (blocks partitioned by range).
__global__ void k_scatter_fused(const int* __restrict__ er, const int* __restrict__ ec,
                                const float* __restrict__ ev,
                                const int* __restrict__ wr_, const int* __restrict__ wc_,
                                const float* __restrict__ wv,
                                const int* __restrict__ bi, const float* __restrict__ bv,
                                float* __restrict__ Ef, float* __restrict__ Wf,
                                float* __restrict__ biasd) {
    int b = blockIdx.x, t = threadIdx.x;
    if (b < NNZ_E / 256) {
        int i = b * 256 + t;
        atomicAdd(&Ef[(size_t)er[i] * F_IN + ec[i]], ev[i]);
    } else if (b < NNZ_E / 256 + NNZ_W / 256) {
        int i = (b - NNZ_E / 256) * 256 + t;
        atomicAdd(&Wf[(size_t)wr_[i] * F_MID + wc_[i]], wv[i]);
    } else {
        int i = t;
        atomicAdd(&biasd[bi[i]], bv[i]);
        i += 256;
        atomicAdd(&biasd[bi[i]], bv[i]);
    }
}

// One launch for all three f32->bf16 conversions.
// blocks [0,2048): x -> x2 left half (row stride F_MID)
// blocks [2048,3072): Ef -> Ebf (contiguous, 1M elems)
// blocks [3072,5120): Wf -> Wbf (contiguous, 2M elems)
__global__ void k_cvt_fused(const float4* __restrict__ x, ushort* __restrict__ x2,
                            const float4* __restrict__ Ef, ushort* __restrict__ Ebf,
                            const float4* __restrict__ Wf, ushort* __restrict__ Wbf) {
    int b = blockIdx.x, t = threadIdx.x;
    if (b < 2048) {
        int i = b * 256 + t;                 // float4 index into x
        int row = i >> 8, c4 = i & 255;      // 256 float4 per row of 1024
        float4 v = x[i];
        ((ushort4*)x2)[(size_t)row * (F_MID / 4) + c4] =
            make_ushort4(f2bf(v.x), f2bf(v.y), f2bf(v.z), f2bf(v.w));
    } else if (b < 3072) {
        int i = (b - 2048) * 256 + t;
        float4 v = Ef[i];
        ((ushort4*)Ebf)[i] = make_ushort4(f2bf(v.x), f2bf(v.y), f2bf(v.z), f2bf(v.w));
    } else {
        int i = (b - 3072) * 256 + t;
        float4 v = Wf[i];
        ((ushort4*)Wbf)[i] = make_ushort4(f2bf(v.x), f2bf(v.y), f2bf(v.z), f2bf(v.w));
    }
}

// C[M,N] = A[M,K] * Bm[N,K]^T.  BM=BN=BK=64; 256 thr = 4 waves (2x2),
// each wave owns 32x32 = 2x2 fragments of 16x16.
// 2-phase double-buffered LDS pipeline; XOR chunk-swizzle on both tiles
// (pre-swizzled global source + swizzled ds_read; LDS dest stays linear).
template <bool RELU_BF16>
__global__ __launch_bounds__(256)
void k_gemm(const ushort* __restrict__ A, int lda,
            const ushort* __restrict__ Bm, int ldb,
            int K,
            const float* __restrict__ bias,
            float* __restrict__ outF,
            ushort* __restrict__ outH, int ldh)
{
    constexpr int BM = 64, BK = 64;
    __shared__ ushort lds[2][2][BM * BK];   // [buf][A|B][64*64]
    const int tid = threadIdx.x;
    const int w = tid >> 6, l = tid & 63;
    const int m0 = blockIdx.x * BM, n0 = blockIdx.y * BM;
    const int wr = w >> 1, wc = w & 1;
    const int la = l & 15;

    // Staging coords: iter i covers 32 rows.  Chunk-swizzle: the lane that
    // writes LDS chunk c' of row r fetches global chunk c' ^ (r&7).
    const int srow = w * 8 + (l >> 3);
    const int ldst = w * 512 + l * 8;        // linear LDS element offset (per 32-row slab)

    f32x4 acc[2][2] = {};
    const int nt = K / BK;

    #define STAGE(buf, k0)                                                        \
        _Pragma("unroll")                                                         \
        for (int i = 0; i < 2; ++i) {                                             \
            int row = i * 32 + srow;                                              \
            int scol = (k0) + ((((l & 7) ^ (row & 7))) << 3);                     \
            gload16(A  + (size_t)(m0 + row) * lda + scol,                         \
                    &lds[buf][0][i * 2048 + ldst]);                               \
            gload16(Bm + (size_t)(n0 + row) * ldb + scol,                         \
                    &lds[buf][1][i * 2048 + ldst]);                               \
        }

    STAGE(0, 0);
    __syncthreads();

    for (int t = 0; t < nt; ++t) {
        const int cur = t & 1;
        if (t + 1 < nt) STAGE(cur ^ 1, (t + 1) * BK);   // prefetch next tile

        const ushort* sA = &lds[cur][0][0];
        const ushort* sB = &lds[cur][1][0];
        #pragma unroll
        for (int ks = 0; ks < 2; ++ks) {
            const int k8 = ks * 4 + (l >> 4);           // 8-elem chunk index
            bf16x8 af[2], bg[2];
            #pragma unroll
            for (int m = 0; m < 2; ++m) {
                int row = wr * 32 + m * 16 + la;
                af[m] = *(const bf16x8*)(sA + row * BK + ((k8 ^ (row & 7)) << 3));
            }
            #pragma unroll
            for (int n = 0; n < 2; ++n) {
                int row = wc * 32 + n * 16 + la;
                bg[n] = *(const bf16x8*)(sB + row * BK + ((k8 ^ (row & 7)) << 3));
            }
            #pragma unroll
            for (int m = 0; m < 2; ++m)
                #pragma unroll
                for (int n = 0; n < 2; ++n)
                    acc[m][n] = __builtin_amdgcn_mfma_f32_16x16x32_bf16(
                        af[m], bg[n], acc[m][n], 0, 0, 0);
        }
        __syncthreads();   // compiler drains vmcnt(0) here -> buf[cur^1] ready
    }

    const int lr = (l >> 4) * 4;
    #pragma unroll
    for (int m = 0; m < 2; ++m) {
        #pragma unroll
        for (int n = 0; n < 2; ++n) {
            const int col = n0 + wc * 32 + n * 16 + la;
            const float bv = RELU_BF16 ? 0.f : bias[col];
            #pragma unroll
            for (int j = 0; j < 4; ++j) {
                const int row = m0 + wr * 32 + m * 16 + lr + j;
                float v = acc[m][n][j];
                if (RELU_BF16) {
                    outH[(size_t)row * ldh + col] = f2bf(fmaxf(v, 0.f));
                } else {
                    outF[(size_t)row * F_OUT + col] = v + bv;
                }
            }
        }
    }
}

extern "C" void kernel_launch(void* const* d_in, const int* in_sizes, int n_in,
                              void* d_out, int out_size, void* d_ws, size_t ws_size,
                              hipStream_t stream) {
    const float* x          = (const float*)d_in[0];
    const int*   embed_rows = (const int*)  d_in[1];
    const int*   embed_cols = (const int*)  d_in[2];
    const float* embed_vals = (const float*)d_in[3];
    const int*   w_rows     = (const int*)  d_in[4];
    const int*   w_cols     = (const int*)  d_in[5];
    const float* w_vals     = (const float*)d_in[6];
    const int*   bias_idx   = (const int*)  d_in[7];
    const float* bias_vals  = (const float*)d_in[8];
    float* out = (float*)d_out;

    // Workspace layout (~26 MB):
    //   [0, 8M)          x2 bf16 [2048][2048]  (left = x, right = relu h)
    //   [8M, 16M)        W_f32 [1024][2048]
    //   [16M, 20M)       E_f32 [1024][1024]
    //   [20M, 20M+4K)    bias f32 [1024]
    //   [20M+4K, 22M+4K) E_bf16 [1024][1024]
    //   [22M+4K, 26M+4K) W_bf16 [1024][2048]   (no aliasing: cvt is fused)
    char* ws = (char*)d_ws;
    ushort* x2    = (ushort*)ws;
    float*  Wf    = (float*)(ws + (8u << 20));
    float*  Ef    = (float*)(ws + (16u << 20));
    float*  biasd = (float*)(ws + (20u << 20));
    ushort* Ebf   = (ushort*)(ws + (20u << 20) + 4096);
    ushort* Wbf   = (ushort*)(ws + (22u << 20) + 4096);

    // 1. zero Wf | Ef | bias (contiguous 12 MB + 4 KB = 786688 float4)
    k_zero4<<<3073, 256, 0, stream>>>((float4*)(ws + (8u << 20)), 786688);

    // 2. densify all sparse inputs (one launch)
    k_scatter_fused<<<NNZ_E / 256 + NNZ_W / 256 + 1, 256, 0, stream>>>(
        embed_rows, embed_cols, embed_vals,
        w_rows, w_cols, w_vals,
        bias_idx, bias_vals, Ef, Wf, biasd);

    // 3. all f32 -> bf16 conversions (one launch)
    k_cvt_fused<<<5120, 256, 0, stream>>>((const float4*)x, x2,
                                          (const float4*)Ef, Ebf,
                                          (const float4*)Wf, Wbf);

    // 4. GEMM1: h = relu(x @ E^T) -> bf16 into x2 right half.  M=2048,N=1024,K=1024
    k_gemm<true><<<dim3(B_SZ / 64, R_EMB / 64), 256, 0, stream>>>(
        x2, F_MID, Ebf, F_IN, F_IN, nullptr, nullptr, x2 + F_IN, F_MID);

    // 5. GEMM2: out = x2 @ W^T + bias.  M=2048,N=1024,K=2048
    k_gemm<false><<<dim3(B_SZ / 64, F_OUT / 64), 256, 0, stream>>>(
        x2, F_MID, Wbf, F_MID, F_MID, biasd, out, nullptr, 0);
}